// Round 20
// baseline (1133.360 us; speedup 1.0000x reference)
//
#include <hip/hip_runtime.h>

#define BATCH 8
#define SEQ 4096
#define DIM 256
#define NH 8
#define DH 32
#define FFN_DIM 1024
#define NL 6
#define M_TOTAL (BATCH * SEQ)   // 32768
#define NCHUNK 32

typedef __attribute__((ext_vector_type(8))) short s16x8;
typedef __attribute__((ext_vector_type(4))) short s16x4;
typedef __attribute__((ext_vector_type(4))) float f32x4;

__device__ __forceinline__ float bf2f(short s) {
    union { unsigned u; float f; } x;
    x.u = ((unsigned)(unsigned short)s) << 16;
    return x.f;
}
__device__ __forceinline__ short f2bf(float f) {
    union { float f; unsigned u; } x;
    x.f = f;
    unsigned r = x.u + 0x7fffu + ((x.u >> 16) & 1u);
    return (short)(r >> 16);
}

#define GLDS16(gp, sp) __builtin_amdgcn_global_load_lds( \
    (const __attribute__((address_space(1))) void*)(gp), \
    (__attribute__((address_space(3))) void*)(sp), 16, 0, 0)

// XCD row-pinning: bijective chunked remap (nwg % 8 == 0).
__device__ __forceinline__ int xcd_chunk(int bx, int nwg) {
    return (bx & 7) * (nwg >> 3) + (bx >> 3);
}

// ---------------- positional encoding add: bf16 + fp32 dual write ----------------
__global__ void peadd_kernel(const float* __restrict__ Q, short* __restrict__ xb,
                             float* __restrict__ xf, int total)
{
    const float c = 9.210340371976184f / 256.f;  // ln(1e4)/256
    for (int idx = blockIdx.x * 256 + threadIdx.x; idx < total; idx += gridDim.x * 256) {
        int d = idx & (DIM - 1);
        int l = (idx >> 8) & (SEQ - 1);
        float rate = __expf(-(float)(d & ~1) * c);
        float ang = (float)l * rate;
        float pe = (d & 1) ? cosf(ang) : sinf(ang);
        float v = Q[idx] + pe;
        xb[idx] = f2bf(v);
        xf[idx] = v;
    }
}

__global__ void kconv_kernel(const float* __restrict__ src, short* __restrict__ dst, int total)
{
    for (int idx = blockIdx.x * 256 + threadIdx.x; idx < total; idx += gridDim.x * 256)
        dst[idx] = f2bf(src[idx]);
}

// ---- weight transpose+convert ----
__global__ void wtrans_kernel(const float* __restrict__ W, short* __restrict__ Wt,
                              int K, int N, int lstride, int rowoff)
{
    __shared__ float tile[32][33];
    int k0 = blockIdx.x * 32, n0 = blockIdx.y * 32;
    const float* Wl = W + (long)blockIdx.z * K * N;
    short* Wtl = Wt + (long)blockIdx.z * lstride;
    int tx = threadIdx.x, ty = threadIdx.y;
#pragma unroll
    for (int r = 0; r < 4; ++r)
        tile[ty + r * 8][tx] = Wl[(long)(k0 + ty + r * 8) * N + n0 + tx];
    __syncthreads();
#pragma unroll
    for (int r = 0; r < 4; ++r)
        Wtl[(long)(rowoff + n0 + ty + r * 8) * K + k0 + tx] = f2bf(tile[tx][ty + r * 8]);
}

// ---- bias pack ----
__global__ void bpack_kernel(const float* __restrict__ bk1, const float* __restrict__ bv1,
                             const float* __restrict__ bk2, const float* __restrict__ bv2,
                             float* __restrict__ o1, float* __restrict__ o2)
{
    int z = blockIdx.x, t = threadIdx.x;
    o1[z * 512 + t] = (t < 256) ? bk1[z * 256 + t] : bv1[z * 256 + t - 256];
    o2[z * 512 + t] = (t < 256) ? bk2[z * 256 + t] : bv2[z * 256 + t - 256];
}

// ---- fused KV projection + partial KV reduction (R19-proven) ----
__global__ __launch_bounds__(256, 2) void kvproj_kernel(
    const short* __restrict__ A, const short* __restrict__ WkvT,
    const float* __restrict__ bkv, float* __restrict__ part)
{
    __shared__ short As[2][128][64];
    __shared__ short Bs[2][128][64];
    const int tid = threadIdx.x;
    const int lane = tid & 63;
    const int wid = tid >> 6;
    const int wr = wid >> 1, wc = wid & 1;
    const int p = blockIdx.y;                         // head pair 0..3
    const int bx = xcd_chunk(blockIdx.x, gridDim.x);
    const int bm = bx * 128;
    const int b = bx >> 5, chunk = bx & 31;
    const int l15 = lane & 15, l4 = lane >> 4;
    const int rl = lane >> 3;
    const int ch = lane & 7;
    const int sw = l15 & 7;

    auto STAGE = [&](int buf, int t) {
        const int k0 = t << 6;
#pragma unroll
        for (int j = 0; j < 8; ++j) {
            int s = wid * 8 + j;
            if (s < 16) {
                int r = s * 8 + rl;
                int cs = ch ^ (r & 7);
                GLDS16(A + (long)(bm + r) * 256 + k0 + cs * 8, &As[buf][s * 8][0]);
            } else {
                int r = (s - 16) * 8 + rl;             // local B row 0..127
                int srcRow = (r < 64) ? (p * 64 + r) : (256 + p * 64 + (r - 64));
                int cs = ch ^ (r & 7);
                GLDS16(WkvT + (long)srcRow * 256 + k0 + cs * 8, &Bs[buf][(s - 16) * 8][0]);
            }
        }
    };

    f32x4 acc[4][4] = {};

    STAGE(0, 0);
    STAGE(1, 1);
    for (int t = 0; t < 4; ++t) {
        const int buf = t & 1;
        if (t < 3) { asm volatile("s_waitcnt vmcnt(8)" ::: "memory"); }
        else       { asm volatile("s_waitcnt vmcnt(0)" ::: "memory"); }
        asm volatile("s_barrier" ::: "memory");
        s16x8 avA[2][4], avB[2][4];
#pragma unroll
        for (int kk = 0; kk < 2; ++kk) {
#pragma unroll
            for (int m = 0; m < 4; ++m)
                avA[kk][m] = *(const s16x8*)&As[buf][wr * 64 + m * 16 + l15][(((kk << 2) | l4) ^ sw) << 3];
#pragma unroll
            for (int n = 0; n < 4; ++n)
                avB[kk][n] = *(const s16x8*)&Bs[buf][wc * 64 + n * 16 + l15][(((kk << 2) | l4) ^ sw) << 3];
        }
        asm volatile("s_waitcnt lgkmcnt(0)" ::: "memory");
        asm volatile("s_barrier" ::: "memory");
        if (t + 2 < 4) STAGE(buf, t + 2);
#pragma unroll
        for (int kk = 0; kk < 2; ++kk)
#pragma unroll
            for (int m = 0; m < 4; ++m)
#pragma unroll
                for (int n = 0; n < 4; ++n)
                    acc[m][n] = __builtin_amdgcn_mfma_f32_16x16x32_bf16(avA[kk][m], avB[kk][n], acc[m][n], 0, 0, 0);
    }
    short (*KfT)[136] = (short(*)[136])&As[0][0][0];
    short (*VfT)[136] = (short(*)[136])&Bs[0][0][0];

#pragma unroll
    for (int m = 0; m < 4; ++m)
#pragma unroll
        for (int n = 0; n < 4; ++n) {
            int c = wc * 64 + n * 16 + l15;
            float bv = (c < 64) ? bkv[p * 64 + c] : bkv[256 + p * 64 + (c - 64)];
#pragma unroll
            for (int j = 0; j < 4; ++j) {
                int r = wr * 64 + m * 16 + l4 * 4 + j;
                float v = acc[m][n][j] + bv;
                if (c < 64) {
                    v = (v > 0.f) ? v + 1.f : __expf(v);
                    KfT[c][r] = f2bf(v);
                } else {
                    VfT[c - 64][r] = f2bf(v);
                }
            }
        }
    __syncthreads();

    const int hl = wid & 1, dt = wid >> 1;
    f32x4 acc2[2] = {{0.f, 0.f, 0.f, 0.f}, {0.f, 0.f, 0.f, 0.f}};
#pragma unroll
    for (int kc = 0; kc < 4; ++kc) {
        s16x8 af = *(const s16x8*)&KfT[hl * 32 + dt * 16 + l15][kc * 32 + l4 * 8];
#pragma unroll
        for (int mt = 0; mt < 2; ++mt) {
            s16x8 bf = *(const s16x8*)&VfT[hl * 32 + mt * 16 + l15][kc * 32 + l4 * 8];
            acc2[mt] = __builtin_amdgcn_mfma_f32_16x16x32_bf16(af, bf, acc2[mt], 0, 0, 0);
        }
    }
    const int h = 2 * p + hl;
    float* pb = part + ((long)(b * 8 + h) * NCHUNK + chunk) * 1056;
#pragma unroll
    for (int mt = 0; mt < 2; ++mt)
#pragma unroll
        for (int j = 0; j < 4; ++j) {
            int d = dt * 16 + l4 * 4 + j;
            int mm = mt * 16 + l15;
            pb[d * 32 + mm] = acc2[mt][j];
        }
    if (tid < 64) {
        float s = 0.f;
#pragma unroll
        for (int rr = 0; rr < 16; ++rr) {
            s16x8 v8 = *(const s16x8*)&KfT[tid][rr * 8];
#pragma unroll
            for (int e = 0; e < 8; ++e) s += bf2f(v8[e]);
        }
        int hh = tid >> 5, dd = tid & 31;
        float* pb2 = part + ((long)(b * 8 + 2 * p + hh) * NCHUNK + chunk) * 1056;
        pb2[1024 + dd] = s;
    }
}

__global__ __launch_bounds__(256) void kvred_kernel(
    const float* __restrict__ part, float* __restrict__ kv, float* __restrict__ ksum)
{
    int bh = blockIdx.x, tid = threadIdx.x;
    const float* pb = part + (long)bh * NCHUNK * 1056;
    float s0 = 0, s1 = 0, s2 = 0, s3 = 0;
    for (int cc = 0; cc < NCHUNK; ++cc) {
        const float* ptr = pb + cc * 1056 + tid * 4;
        s0 += ptr[0]; s1 += ptr[1]; s2 += ptr[2]; s3 += ptr[3];
    }
    float* kb = kv + (long)bh * 1024 + tid * 4;
    kb[0] = s0; kb[1] = s1; kb[2] = s2; kb[3] = s3;
    if (tid < 32) {
        float ss = 0;
        for (int cc = 0; cc < NCHUNK; ++cc) ss += pb[cc * 1056 + 1024 + tid];
        ksum[bh * 32 + tid] = ss;
    }
}

// ---- fused FFN v4 (R15-proven): wave-private B staging, BM=64 ----
__global__ __launch_bounds__(512, 1) void ffnln_kernel(
    const short* __restrict__ X, const short* __restrict__ W1t,
    const float* __restrict__ b1, const short* __restrict__ W2t,
    const float* __restrict__ b2,
    const float* __restrict__ gam, const float* __restrict__ bet,
    const float* __restrict__ Fin, float* __restrict__ Fout,
    short* __restrict__ xb)
{
    __shared__ short xs[4][64][64];
    __shared__ short hs[4][64][64];
    __shared__ short Bs[8][2][32][64];
    __shared__ float partS[8][64];
    __shared__ float partQ[8][64];
    __shared__ float muA[64];
    __shared__ float rsA[64];
    const int tid = threadIdx.x;
    const int lane = tid & 63;
    const int w = tid >> 6;
    const int bm = xcd_chunk(blockIdx.x, gridDim.x) * 64;
    const int l15 = lane & 15, l4 = lane >> 4;
    const int rl = lane >> 3;
    const int ch = lane & 7;
    const int sw = l15 & 7;

#pragma unroll
    for (int j = 0; j < 4; ++j) {
        int s = w * 4 + j;
        int kt = s >> 3, rg = s & 7;
        int r = rg * 8 + rl;
        int cs = ch ^ (r & 7);
        GLDS16(X + (long)(bm + r) * 256 + kt * 64 + cs * 8, &xs[kt][rg * 8][0]);
    }
    auto STAGEB = [&](int buf, int v) {
        int hc = v >> 3, u = v & 7;
#pragma unroll
        for (int j = 0; j < 4; ++j) {
            int lr = j * 8 + rl;
            int r = w * 32 + lr;
            int cs = ch ^ (lr & 7);
            const short* src = (u < 4)
                ? W1t + (long)(hc * 256 + r) * 256 + u * 64 + cs * 8
                : W2t + (long)r * 1024 + hc * 256 + (u - 4) * 64 + cs * 8;
            GLDS16(src, &Bs[w][buf][j * 8][0]);
        }
    };

    STAGEB(0, 0);
    STAGEB(1, 1);
    asm volatile("s_waitcnt vmcnt(8)" ::: "memory");
    asm volatile("s_barrier" ::: "memory");

    f32x4 facc[4][2] = {};

    for (int hc = 0; hc < 4; ++hc) {
        f32x4 hacc[4][2] = {};
#pragma unroll
        for (int u = 0; u < 4; ++u) {
            const int v = hc * 8 + u;
            const int buf = v & 1;
            asm volatile("s_waitcnt vmcnt(4)" ::: "memory");
            s16x8 avA[2][4], avB[2][2];
#pragma unroll
            for (int kk = 0; kk < 2; ++kk) {
#pragma unroll
                for (int n = 0; n < 2; ++n)
                    avB[kk][n] = *(const s16x8*)&Bs[w][buf][n * 16 + l15][(((kk << 2) | l4) ^ sw) << 3];
#pragma unroll
                for (int m = 0; m < 4; ++m)
                    avA[kk][m] = *(const s16x8*)&xs[u][m * 16 + l15][(((kk << 2) | l4) ^ sw) << 3];
            }
            asm volatile("s_waitcnt lgkmcnt(0)" ::: "memory");
            STAGEB(buf, v + 2);
#pragma unroll
            for (int kk = 0; kk < 2; ++kk)
#pragma unroll
                for (int m = 0; m < 4; ++m)
#pragma unroll
                    for (int n = 0; n < 2; ++n)
                        hacc[m][n] = __builtin_amdgcn_mfma_f32_16x16x32_bf16(avA[kk][m], avB[kk][n], hacc[m][n], 0, 0, 0);
        }
        asm volatile("s_waitcnt lgkmcnt(0)" ::: "memory");
        asm volatile("s_barrier" ::: "memory");
#pragma unroll
        for (int m = 0; m < 4; ++m)
#pragma unroll
            for (int n = 0; n < 2; ++n) {
                int c = w * 32 + n * 16 + l15;
                float bv = b1[hc * 256 + c];
#pragma unroll
                for (int j = 0; j < 4; ++j) {
                    int r = m * 16 + l4 * 4 + j;
                    float hv = fmaxf(hacc[m][n][j] + bv, 0.f);
                    int kt = c >> 6, cc = (c & 63) >> 3;
                    hs[kt][r][((cc ^ (r & 7)) << 3) + (c & 7)] = f2bf(hv);
                }
            }
        asm volatile("s_waitcnt lgkmcnt(0)" ::: "memory");
        asm volatile("s_barrier" ::: "memory");
#pragma unroll
        for (int u = 4; u < 8; ++u) {
            const int v = hc * 8 + u;
            const int buf = v & 1;
            if (v < 31) { asm volatile("s_waitcnt vmcnt(4)" ::: "memory"); }
            else        { asm volatile("s_waitcnt vmcnt(0)" ::: "memory"); }
            s16x8 avA[2][4], avB[2][2];
#pragma unroll
            for (int kk = 0; kk < 2; ++kk) {
#pragma unroll
                for (int n = 0; n < 2; ++n)
                    avB[kk][n] = *(const s16x8*)&Bs[w][buf][n * 16 + l15][(((kk << 2) | l4) ^ sw) << 3];
#pragma unroll
                for (int m = 0; m < 4; ++m)
                    avA[kk][m] = *(const s16x8*)&hs[u - 4][m * 16 + l15][(((kk << 2) | l4) ^ sw) << 3];
            }
            asm volatile("s_waitcnt lgkmcnt(0)" ::: "memory");
            if (v + 2 < 32) STAGEB(buf, v + 2);
#pragma unroll
            for (int kk = 0; kk < 2; ++kk)
#pragma unroll
                for (int m = 0; m < 4; ++m)
#pragma unroll
                    for (int n = 0; n < 2; ++n)
                        facc[m][n] = __builtin_amdgcn_mfma_f32_16x16x32_bf16(avA[kk][m], avB[kk][n], facc[m][n], 0, 0, 0);
        }
    }

#pragma unroll
    for (int m = 0; m < 4; ++m)
#pragma unroll
        for (int n = 0; n < 2; ++n) {
            int col = w * 32 + n * 16 + l15;
            float bv = b2[col];
#pragma unroll
            for (int j = 0; j < 4; ++j) {
                int r = m * 16 + l4 * 4 + j;
                float v = fmaxf(facc[m][n][j] + bv, 0.f);
                v += Fin[(long)(bm + r) * DIM + col];
                facc[m][n][j] = v;
            }
        }
#pragma unroll
    for (int m = 0; m < 4; ++m)
#pragma unroll
        for (int j = 0; j < 4; ++j) {
            float s = facc[m][0][j] + facc[m][1][j];
            float q = facc[m][0][j] * facc[m][0][j] + facc[m][1][j] * facc[m][1][j];
#pragma unroll
            for (int off = 1; off < 16; off <<= 1) {
                s += __shfl_xor(s, off);
                q += __shfl_xor(q, off);
            }
            if (l15 == 0) {
                partS[w][m * 16 + l4 * 4 + j] = s;
                partQ[w][m * 16 + l4 * 4 + j] = q;
            }
        }
    __syncthreads();
    if (tid < 64) {
        float S = 0, Qq = 0;
#pragma unroll
        for (int ww = 0; ww < 8; ++ww) { S += partS[ww][tid]; Qq += partQ[ww][tid]; }
        float mu = S * (1.f / 256.f);
        float var = Qq * (1.f / 256.f) - mu * mu;
        muA[tid] = mu;
        rsA[tid] = rsqrtf(var + 1e-3f);
    }
    __syncthreads();
#pragma unroll
    for (int m = 0; m < 4; ++m)
#pragma unroll
        for (int j = 0; j < 4; ++j) {
            int r = m * 16 + l4 * 4 + j;
            float mu = muA[r], rs = rsA[r];
#pragma unroll
            for (int n = 0; n < 2; ++n) {
                int col = w * 32 + n * 16 + l15;
                float t = (facc[m][n][j] - mu) * rs * gam[col] + bet[col];
                long o = (long)(bm + r) * DIM + col;
                xb[o] = f2bf(t);
                Fout[o] = t;
            }
        }
}

// ---- MEGA-fused qattn (R16-proven) + T14 Fin prefetch ----
__global__ __launch_bounds__(512, 1) void qattn_kernel(
    const short* __restrict__ A, const short* __restrict__ Bt,
    const float* __restrict__ bias, const float* __restrict__ kv,
    const float* __restrict__ ksum,
    const short* __restrict__ WoT, const float* __restrict__ bo,
    const float* __restrict__ gam, const float* __restrict__ bet,
    const float* __restrict__ Fin, float* __restrict__ Fout,
    short* __restrict__ xb)
{
    __shared__ char smem[140288];
    short (*As)[128][64] = (short(*)[128][64])(smem);
    short (*Bs)[256][64] = (short(*)[256][64])(smem + 32768);
    short (*QfL)[256] = (short(*)[256])(smem);
    short (*kvbT)[32][48] = (short(*)[32][48])(smem + 98304);
    float* ksumAll = (float*)(smem + 122880);
    float (*partDenH)[128] = (float(*)[128])(smem + 123904);
    short (*oL)[256] = (short(*)[256])(smem + 65536);
    short (*WoS)[256][64] = (short(*)[256][64])(smem);
    float (*partS)[128] = (float(*)[128])(smem + 131072);
    float (*partQ)[128] = (float(*)[128])(smem + 135168);
    float* muA = (float*)(smem + 139264);
    float* rsA = (float*)(smem + 139776);

    const int tid = threadIdx.x;
    const int lane = tid & 63;
    const int w = tid >> 6;
    const int wr = w >> 2, wc = w & 3;
    const int bm = xcd_chunk(blockIdx.x, gridDim.x) * 128;
    const int b = bm >> 12;
    const int l15 = lane & 15, l4 = lane >> 4;
    const int rl = lane >> 3;
    const int ch = lane & 7;
    const int sw = l15 & 7;

    for (int idx = tid; idx < 8192; idx += 512) {
        int h = idx >> 10, j = idx & 1023, d = j >> 5, m = j & 31;
        kvbT[h][m][d] = f2bf(kv[(long)(b * 8 + h) * 1024 + j]);
    }
    if (tid < 256) ksumAll[tid] = ksum[(b * 8 + (tid >> 5)) * 32 + (tid & 31)];

    auto STAGE = [&](int buf, int t) {
        const int k0 = t << 6;
#pragma unroll
        for (int j = 0; j < 6; ++j) {
            int s = w * 6 + j;
            if (s < 16) {
                int r = s * 8 + rl;
                int cs = ch ^ (r & 7);
                GLDS16(A + (long)(bm + r) * 256 + k0 + cs * 8, &As[buf][s * 8][0]);
            } else {
                int r = (s - 16) * 8 + rl;
                int cs = ch ^ (r & 7);
                GLDS16(Bt + (long)r * 256 + k0 + cs * 8, &Bs[buf][(s - 16) * 8][0]);
            }
        }
    };

    f32x4 acc[4][4] = {};

    STAGE(0, 0);
    STAGE(1, 1);
#pragma unroll
    for (int t = 0; t < 4; ++t) {
        const int buf = t & 1;
        if (t < 3) { asm volatile("s_waitcnt vmcnt(6)" ::: "memory"); }
        else       { asm volatile("s_waitcnt vmcnt(0)" ::: "memory"); }
        asm volatile("s_barrier" ::: "memory");
        s16x8 avA[2][4], avB[2][4];
#pragma unroll
        for (int kk = 0; kk < 2; ++kk) {
#pragma unroll
            for (int m = 0; m < 4; ++m)
                avA[kk][m] = *(const s16x8*)&As[buf][wr * 64 + m * 16 + l15][(((kk << 2) | l4) ^ sw) << 3];
#pragma unroll
            for (int n = 0; n < 4; ++n)
                avB[kk][n] = *(const s16x8*)&Bs[buf][wc * 64 + n * 16 + l15][(((kk << 2) | l4) ^ sw) << 3];
        }
        asm volatile("s_waitcnt lgkmcnt(0)" ::: "memory");
        asm volatile("s_barrier" ::: "memory");
        if (t < 2) STAGE(buf, t + 2);
#pragma unroll
        for (int kk = 0; kk < 2; ++kk)
#pragma unroll
            for (int m = 0; m < 4; ++m)
#pragma unroll
                for (int n = 0; n < 4; ++n)
                    acc[m][n] = __builtin_amdgcn_mfma_f32_16x16x32_bf16(avA[kk][m], avB[kk][n], acc[m][n], 0, 0, 0);
    }

    // phase 1.5
#pragma unroll
    for (int m = 0; m < 4; ++m)
#pragma unroll
        for (int n = 0; n < 4; ++n) {
            int col = wc * 64 + n * 16 + l15;
            float bv = bias[col];
#pragma unroll
            for (int j = 0; j < 4; ++j) {
                float v = acc[m][n][j] + bv;
                acc[m][n][j] = (v > 0.f) ? v + 1.f : __expf(v);
            }
        }
#pragma unroll
    for (int m = 0; m < 4; ++m)
#pragma unroll
        for (int j = 0; j < 4; ++j) {
            float p0 = acc[m][0][j] * ksumAll[wc * 64 + l15]
                     + acc[m][1][j] * ksumAll[wc * 64 + 16 + l15];
            float p1 = acc[m][2][j] * ksumAll[wc * 64 + 32 + l15]
                     + acc[m][3][j] * ksumAll[wc * 64 + 48 + l15];
#pragma unroll
            for (int off = 1; off < 16; off <<= 1) {
                p0 += __shfl_xor(p0, off);
                p1 += __shfl_xor(p1, off);
            }
            if (l15 == 0) {
                int r = wr * 64 + m * 16 + l4 * 4 + j;
                partDenH[wc * 2 + 0][r] = p0;
                partDenH[wc * 2 + 1][r] = p1;
            }
        }
#pragma unroll
    for (int m = 0; m < 4; ++m)
#pragma unroll
        for (int n = 0; n < 4; ++n) {
            int col = wc * 64 + n * 16 + l15;
#pragma unroll
            for (int j = 0; j < 4; ++j) {
                int r = wr * 64 + m * 16 + l4 * 4 + j;
                int chunk = (col >> 3) ^ (r & 7);
                QfL[r][chunk * 8 + (col & 7)] = f2bf(acc[m][n][j]);
            }
        }
    __syncthreads();

    // T14: prefetch Fin (epilogue residual) early; latency hides under phase 2/3.
    float fin[8][2][4];
#pragma unroll
    for (int m = 0; m < 8; ++m)
#pragma unroll
        for (int n = 0; n < 2; ++n)
#pragma unroll
            for (int j = 0; j < 4; ++j)
                fin[m][n][j] = Fin[(long)(bm + m * 16 + l4 * 4 + j) * DIM + w * 32 + n * 16 + l15];

    // phase 2 preload (kvbT + partDenH die after this; oL overlays them)
    const int h = w;
    s16x8 afr[2];
#pragma unroll
    for (int ct = 0; ct < 2; ++ct)
        afr[ct] = *(const s16x8*)&kvbT[h][ct * 16 + l15][l4 * 8];
    float zv[8];
#pragma unroll
    for (int rt = 0; rt < 8; ++rt)
        zv[rt] = 1.f / (partDenH[h][rt * 16 + l15] + 1e-6f);
    asm volatile("s_waitcnt lgkmcnt(0)" ::: "memory");
    __syncthreads();

    // phase 2
#pragma unroll
    for (int rt = 0; rt < 8; ++rt) {
        int r = rt * 16 + l15;
        int qchunk = (h * 4 + l4) ^ (r & 7);
        s16x8 bfr = *(const s16x8*)&QfL[r][qchunk * 8];
#pragma unroll
        for (int ct = 0; ct < 2; ++ct) {
            f32x4 zero = {0.f, 0.f, 0.f, 0.f};
            f32x4 po = __builtin_amdgcn_mfma_f32_16x16x32_bf16(afr[ct], bfr, zero, 0, 0, 0);
            s16x4 o4;
#pragma unroll
            for (int j = 0; j < 4; ++j) o4[j] = f2bf(po[j] * zv[rt]);
            int c0 = h * 32 + ct * 16 + l4 * 4;
            int cc = c0 >> 3;
            *(s16x4*)&oL[r][((cc ^ (r & 7)) << 3) + (c0 & 7)] = o4;
        }
    }
    asm volatile("s_waitcnt lgkmcnt(0)" ::: "memory");
    __syncthreads();

    // phase 3
    auto STAGEWO = [&](int buf, int t) {
#pragma unroll
        for (int j = 0; j < 4; ++j) {
            int lr = j * 8 + rl;
            int r = w * 32 + lr;
            int cs = ch ^ (lr & 7);
            GLDS16(WoT + (long)r * 256 + t * 64 + cs * 8, &WoS[buf][w * 32 + j * 8][0]);
        }
    };
    STAGEWO(0, 0);
    STAGEWO(1, 1);

    f32x4 facc[8][2] = {};
#pragma unroll
    for (int t = 0; t < 4; ++t) {
        const int buf = t & 1;
        if (t < 3) { asm volatile("s_waitcnt vmcnt(4)" ::: "memory"); }
        else       { asm volatile("s_waitcnt vmcnt(0)" ::: "memory"); }
#pragma unroll
        for (int kk = 0; kk < 2; ++kk) {
            s16x8 avB0 = *(const s16x8*)&WoS[buf][w * 32 + l15][(((kk << 2) | l4) ^ sw) << 3];
            s16x8 avB1 = *(const s16x8*)&WoS[buf][w * 32 + 16 + l15][(((kk << 2) | l4) ^ sw) << 3];
#pragma unroll
            for (int m = 0; m < 8; ++m) {
                int ar = m * 16 + l15;
                s16x8 avA = *(const s16x8*)&oL[ar][(t * 8 + (((kk << 2) | l4) ^ sw)) << 3];
                facc[m][0] = __builtin_amdgcn_mfma_f32_16x16x32_bf16(avA, avB0, facc[m][0], 0, 0, 0);
                facc[m][1] = __builtin_amdgcn_mfma_f32_16x16x32_bf16(avA, avB1, facc[m][1], 0, 0, 0);
            }
        }
        asm volatile("s_waitcnt lgkmcnt(0)" ::: "memory");
        if (t + 2 < 4) STAGEWO(buf, t + 2);
    }

    // epilogue: bias + prefetched fp32 residual, row LN over 128 rows
#pragma unroll
    for (int m = 0; m < 8; ++m)
#pragma unroll
        for (int n = 0; n < 2; ++n) {
            int col = w * 32 + n * 16 + l15;
            float bv = bo[col];
#pragma unroll
            for (int j = 0; j < 4; ++j) {
                float v = facc[m][n][j] + bv;
                v += fin[m][n][j];
                facc[m][n][j] = v;
            }
        }
#pragma unroll
    for (int m = 0; m < 8; ++m)
#pragma unroll
        for (int j = 0; j < 4; ++j) {
            float s = facc[m][0][j] + facc[m][1][j];
            float q = facc[m][0][j] * facc[m][0][j] + facc[m][1][j] * facc[m][1][j];
#pragma unroll
            for (int off = 1; off < 16; off <<= 1) {
                s += __shfl_xor(s, off);
                q += __shfl_xor(q, off);
            }
            if (l15 == 0) {
                partS[w][m * 16 + l4 * 4 + j] = s;
                partQ[w][m * 16 + l4 * 4 + j] = q;
            }
        }
    __syncthreads();
    if (tid < 128) {
        float S = 0, Qq = 0;
#pragma unroll
        for (int ww = 0; ww < 8; ++ww) { S += partS[ww][tid]; Qq += partQ[ww][tid]; }
        float mu = S * (1.f / 256.f);
        float var = Qq * (1.f / 256.f) - mu * mu;
        muA[tid] = mu;
        rsA[tid] = rsqrtf(var + 1e-3f);
    }
    __syncthreads();
#pragma unroll
    for (int m = 0; m < 8; ++m)
#pragma unroll
        for (int j = 0; j < 4; ++j) {
            int r = m * 16 + l4 * 4 + j;
            float mu = muA[r], rs = rsA[r];
#pragma unroll
            for (int n = 0; n < 2; ++n) {
                int col = w * 32 + n * 16 + l15;
                float t = (facc[m][n][j] - mu) * rs * gam[col] + bet[col];
                long o = (long)(bm + r) * DIM + col;
                xb[o] = f2bf(t);
                Fout[o] = t;
            }
        }
}

// =======================================================================================
extern "C" void kernel_launch(void* const* d_in, const int* in_sizes, int n_in,
                              void* d_out, int out_size, void* d_ws, size_t ws_size,
                              hipStream_t stream)
{
    const float* Qin = (const float*)d_in[0];
    const float* Kin = (const float*)d_in[1];
    const float* Wq1 = (const float*)d_in[2];
    const float* Wk1 = (const float*)d_in[3];
    const float* Wv1 = (const float*)d_in[4];
    const float* Wo1 = (const float*)d_in[5];
    const float* bq1 = (const float*)d_in[6];
    const float* bk1 = (const float*)d_in[7];
    const float* bv1 = (const float*)d_in[8];
    const float* bo1 = (const float*)d_in[9];
    const float* Wq2 = (const float*)d_in[10];
    const float* Wk2 = (const float*)d_in[11];
    const float* Wv2 = (const float*)d_in[12];
    const float* Wo2 = (const float*)d_in[13];
    const float* bq2 = (const float*)d_in[14];
    const float* bk2 = (const float*)d_in[15];
    const float* bv2 = (const float*)d_in[16];
    const float* bo2 = (const float*)d_in[17];
    const float* Wf1 = (const float*)d_in[18];
    const float* bf1 = (const float*)d_in[19];
    const float* Wf2 = (const float*)d_in[20];
    const float* bf2 = (const float*)d_in[21];
    const float* ln1g = (const float*)d_in[22];
    const float* ln1b = (const float*)d_in[23];
    const float* ln2g = (const float*)d_in[24];
    const float* ln2b = (const float*)d_in[25];
    const float* ln3g = (const float*)d_in[26];
    const float* ln3b = (const float*)d_in[27];
    (void)in_sizes; (void)n_in; (void)out_size;

    const size_t NEED = 117841920ULL;   // round-2-proven guard (actual use ~94 MB)
    if (ws_size < NEED) return;

    char* ws = (char*)d_ws;
    size_t off = 0;
    auto alloc = [&](size_t bytes) -> void* {
        void* p = ws + off;
        off = (off + bytes + 255) & ~(size_t)255;
        return p;
    };
    const size_t ACT_E = (size_t)M_TOTAL * DIM;

    short* wkv1t = (short*)alloc((size_t)NL * 512 * 256 * 2);
    short* wkv2t = (short*)alloc((size_t)NL * 512 * 256 * 2);
    short* wq1t  = (short*)alloc((size_t)NL * 65536 * 2);
    short* wo1t  = (short*)alloc((size_t)NL * 65536 * 2);
    short* wq2t  = (short*)alloc((size_t)NL * 65536 * 2);
    short* wo2t  = (short*)alloc((size_t)NL * 65536 * 2);
    short* wf1t  = (short*)alloc((size_t)NL * 262144 * 2);
    short* wf2t  = (short*)alloc((size_t)NL * 262144 * 2);
    float* bkv1  = (float*)alloc((size_t)NL * 512 * 4);
    float* bkv2  = (float*)alloc((size_t)NL * 512 * 4);
    short* kbf = (short*)alloc(ACT_E * 2);
    short* A0  = (short*)alloc(ACT_E * 2);
    float* Fx  = (float*)alloc(ACT_E * 4);
    float* part = (float*)alloc((size_t)64 * NCHUNK * 1056 * 4);
    float* kvb  = (float*)alloc((size_t)64 * 1024 * 4);
    float* ksb  = (float*)alloc((size_t)64 * 32 * 4);
    float* kvb2 = (float*)alloc((size_t)NL * 64 * 1024 * 4);   // precomputed cross-attn KV
    float* ksb2 = (float*)alloc((size_t)NL * 64 * 32 * 4);

    peadd_kernel<<<2048, 256, 0, stream>>>(Qin, A0, Fx, (int)ACT_E);
    kconv_kernel<<<2048, 256, 0, stream>>>(Kin, kbf, (int)ACT_E);
    wtrans_kernel<<<dim3(8, 8, NL), dim3(32, 8), 0, stream>>>(Wk1, wkv1t, 256, 256, 512 * 256, 0);
    wtrans_kernel<<<dim3(8, 8, NL), dim3(32, 8), 0, stream>>>(Wv1, wkv1t, 256, 256, 512 * 256, 256);
    wtrans_kernel<<<dim3(8, 8, NL), dim3(32, 8), 0, stream>>>(Wk2, wkv2t, 256, 256, 512 * 256, 0);
    wtrans_kernel<<<dim3(8, 8, NL), dim3(32, 8), 0, stream>>>(Wv2, wkv2t, 256, 256, 512 * 256, 256);
    wtrans_kernel<<<dim3(8, 8, NL), dim3(32, 8), 0, stream>>>(Wq1, wq1t, 256, 256, 65536, 0);
    wtrans_kernel<<<dim3(8, 8, NL), dim3(32, 8), 0, stream>>>(Wo1, wo1t, 256, 256, 65536, 0);
    wtrans_kernel<<<dim3(8, 8, NL), dim3(32, 8), 0, stream>>>(Wq2, wq2t, 256, 256, 65536, 0);
    wtrans_kernel<<<dim3(8, 8, NL), dim3(32, 8), 0, stream>>>(Wo2, wo2t, 256, 256, 65536, 0);
    wtrans_kernel<<<dim3(8, 32, NL), dim3(32, 8), 0, stream>>>(Wf1, wf1t, 256, 1024, 262144, 0);
    wtrans_kernel<<<dim3(32, 8, NL), dim3(32, 8), 0, stream>>>(Wf2, wf2t, 1024, 256, 262144, 0);
    bpack_kernel<<<NL, 512, 0, stream>>>(bk1, bv1, bk2, bv2, bkv1, bkv2);

    dim3 blk(256), blk512(512);

    // ---- hoisted: cross-attention KV for all layers (depends only on kbf+weights).
    // Consecutive runs keep kbf L2/L3-hot.
    for (int z = 0; z < NL; ++z) {
        kvproj_kernel<<<dim3(256, 4), blk, 0, stream>>>(kbf, wkv2t + (size_t)z * 512 * 256,
            bkv2 + z * 512, part);
        kvred_kernel<<<64, blk, 0, stream>>>(part, kvb2 + (size_t)z * 64 * 1024,
            ksb2 + (size_t)z * 64 * 32);
    }

    for (int i = 0; i < NL; ++i) {
        const short* wkv1i = wkv1t + (size_t)i * 512 * 256;
        const short* wq1i = wq1t + (size_t)i * 65536;
        const short* wo1i = wo1t + (size_t)i * 65536;
        const short* wq2i = wq2t + (size_t)i * 65536;
        const short* wo2i = wo2t + (size_t)i * 65536;
        const short* wf1i = wf1t + (size_t)i * 262144;
        const short* wf2i = wf2t + (size_t)i * 262144;

        // ---- self linear-attention (x1 -> x2): 3 dispatches
        kvproj_kernel<<<dim3(256, 4), blk, 0, stream>>>(A0, wkv1i, bkv1 + i * 512, part);
        kvred_kernel<<<64, blk, 0, stream>>>(part, kvb, ksb);
        qattn_kernel<<<M_TOTAL / 128, blk512, 0, stream>>>(A0, wq1i, bq1 + i * 256, kvb, ksb,
            wo1i, bo1 + i * 256, ln1g + i * 256, ln1b + i * 256, Fx, Fx, A0);

        // ---- cross linear-attention (x2, K -> x3): 1 dispatch (KV precomputed)
        qattn_kernel<<<M_TOTAL / 128, blk512, 0, stream>>>(A0, wq2i, bq2 + i * 256,
            kvb2 + (size_t)i * 64 * 1024, ksb2 + (size_t)i * 64 * 32,
            wo2i, bo2 + i * 256, ln2g + i * 256, ln2b + i * 256, Fx, Fx, A0);

        // ---- fused FFN + LN (x3 -> x1'): 1 dispatch
        ffnln_kernel<<<M_TOTAL / 64, blk512, 0, stream>>>(A0, wf1i, bf1 + i * 1024,
            wf2i, bf2 + i * 256, ln3g + i * 256, ln3b + i * 256,
            Fx, (i == NL - 1) ? (float*)d_out : Fx, A0);
    }
}

// Round 21
// 1123.442 us; speedup vs baseline: 1.0088x; 1.0088x over previous
//
#include <hip/hip_runtime.h>

#define BATCH 8
#define SEQ 4096
#define DIM 256
#define NH 8
#define DH 32
#define FFN_DIM 1024
#define NL 6
#define M_TOTAL (BATCH * SEQ)   // 32768
#define NCHUNK 32

typedef __attribute__((ext_vector_type(8))) short s16x8;
typedef __attribute__((ext_vector_type(4))) short s16x4;
typedef __attribute__((ext_vector_type(4))) float f32x4;

__device__ __forceinline__ float bf2f(short s) {
    union { unsigned u; float f; } x;
    x.u = ((unsigned)(unsigned short)s) << 16;
    return x.f;
}
__device__ __forceinline__ short f2bf(float f) {
    union { float f; unsigned u; } x;
    x.f = f;
    unsigned r = x.u + 0x7fffu + ((x.u >> 16) & 1u);
    return (short)(r >> 16);
}

#define GLDS16(gp, sp) __builtin_amdgcn_global_load_lds( \
    (const __attribute__((address_space(1))) void*)(gp), \
    (__attribute__((address_space(3))) void*)(sp), 16, 0, 0)

// XCD row-pinning: bijective chunked remap (nwg % 8 == 0).
__device__ __forceinline__ int xcd_chunk(int bx, int nwg) {
    return (bx & 7) * (nwg >> 3) + (bx >> 3);
}

// ---------------- positional encoding add: bf16 + fp32 dual write ----------------
__global__ void peadd_kernel(const float* __restrict__ Q, short* __restrict__ xb,
                             float* __restrict__ xf, int total)
{
    const float c = 9.210340371976184f / 256.f;  // ln(1e4)/256
    for (int idx = blockIdx.x * 256 + threadIdx.x; idx < total; idx += gridDim.x * 256) {
        int d = idx & (DIM - 1);
        int l = (idx >> 8) & (SEQ - 1);
        float rate = __expf(-(float)(d & ~1) * c);
        float ang = (float)l * rate;
        float pe = (d & 1) ? cosf(ang) : sinf(ang);
        float v = Q[idx] + pe;
        xb[idx] = f2bf(v);
        xf[idx] = v;
    }
}

__global__ void kconv_kernel(const float* __restrict__ src, short* __restrict__ dst, int total)
{
    for (int idx = blockIdx.x * 256 + threadIdx.x; idx < total; idx += gridDim.x * 256)
        dst[idx] = f2bf(src[idx]);
}

// ---- weight transpose+convert ----
__global__ void wtrans_kernel(const float* __restrict__ W, short* __restrict__ Wt,
                              int K, int N, int lstride, int rowoff)
{
    __shared__ float tile[32][33];
    int k0 = blockIdx.x * 32, n0 = blockIdx.y * 32;
    const float* Wl = W + (long)blockIdx.z * K * N;
    short* Wtl = Wt + (long)blockIdx.z * lstride;
    int tx = threadIdx.x, ty = threadIdx.y;
#pragma unroll
    for (int r = 0; r < 4; ++r)
        tile[ty + r * 8][tx] = Wl[(long)(k0 + ty + r * 8) * N + n0 + tx];
    __syncthreads();
#pragma unroll
    for (int r = 0; r < 4; ++r)
        Wtl[(long)(rowoff + n0 + ty + r * 8) * K + k0 + tx] = f2bf(tile[tx][ty + r * 8]);
}

// ---- bias pack ----
__global__ void bpack_kernel(const float* __restrict__ bk1, const float* __restrict__ bv1,
                             const float* __restrict__ bk2, const float* __restrict__ bv2,
                             float* __restrict__ o1, float* __restrict__ o2)
{
    int z = blockIdx.x, t = threadIdx.x;
    o1[z * 512 + t] = (t < 256) ? bk1[z * 256 + t] : bv1[z * 256 + t - 256];
    o2[z * 512 + t] = (t < 256) ? bk2[z * 256 + t] : bv2[z * 256 + t - 256];
}

// ---- fused KV projection + partial KV reduction (R19-proven) ----
__global__ __launch_bounds__(256, 2) void kvproj_kernel(
    const short* __restrict__ A, const short* __restrict__ WkvT,
    const float* __restrict__ bkv, float* __restrict__ part)
{
    __shared__ short As[2][128][64];
    __shared__ short Bs[2][128][64];
    const int tid = threadIdx.x;
    const int lane = tid & 63;
    const int wid = tid >> 6;
    const int wr = wid >> 1, wc = wid & 1;
    const int p = blockIdx.y;                         // head pair 0..3
    const int bx = xcd_chunk(blockIdx.x, gridDim.x);
    const int bm = bx * 128;
    const int b = bx >> 5, chunk = bx & 31;
    const int l15 = lane & 15, l4 = lane >> 4;
    const int rl = lane >> 3;
    const int ch = lane & 7;
    const int sw = l15 & 7;

    auto STAGE = [&](int buf, int t) {
        const int k0 = t << 6;
#pragma unroll
        for (int j = 0; j < 8; ++j) {
            int s = wid * 8 + j;
            if (s < 16) {
                int r = s * 8 + rl;
                int cs = ch ^ (r & 7);
                GLDS16(A + (long)(bm + r) * 256 + k0 + cs * 8, &As[buf][s * 8][0]);
            } else {
                int r = (s - 16) * 8 + rl;             // local B row 0..127
                int srcRow = (r < 64) ? (p * 64 + r) : (256 + p * 64 + (r - 64));
                int cs = ch ^ (r & 7);
                GLDS16(WkvT + (long)srcRow * 256 + k0 + cs * 8, &Bs[buf][(s - 16) * 8][0]);
            }
        }
    };

    f32x4 acc[4][4] = {};

    STAGE(0, 0);
    STAGE(1, 1);
    for (int t = 0; t < 4; ++t) {
        const int buf = t & 1;
        if (t < 3) { asm volatile("s_waitcnt vmcnt(8)" ::: "memory"); }
        else       { asm volatile("s_waitcnt vmcnt(0)" ::: "memory"); }
        asm volatile("s_barrier" ::: "memory");
        s16x8 avA[2][4], avB[2][4];
#pragma unroll
        for (int kk = 0; kk < 2; ++kk) {
#pragma unroll
            for (int m = 0; m < 4; ++m)
                avA[kk][m] = *(const s16x8*)&As[buf][wr * 64 + m * 16 + l15][(((kk << 2) | l4) ^ sw) << 3];
#pragma unroll
            for (int n = 0; n < 4; ++n)
                avB[kk][n] = *(const s16x8*)&Bs[buf][wc * 64 + n * 16 + l15][(((kk << 2) | l4) ^ sw) << 3];
        }
        asm volatile("s_waitcnt lgkmcnt(0)" ::: "memory");
        asm volatile("s_barrier" ::: "memory");
        if (t + 2 < 4) STAGE(buf, t + 2);
#pragma unroll
        for (int kk = 0; kk < 2; ++kk)
#pragma unroll
            for (int m = 0; m < 4; ++m)
#pragma unroll
                for (int n = 0; n < 4; ++n)
                    acc[m][n] = __builtin_amdgcn_mfma_f32_16x16x32_bf16(avA[kk][m], avB[kk][n], acc[m][n], 0, 0, 0);
    }
    short (*KfT)[136] = (short(*)[136])&As[0][0][0];
    short (*VfT)[136] = (short(*)[136])&Bs[0][0][0];

#pragma unroll
    for (int m = 0; m < 4; ++m)
#pragma unroll
        for (int n = 0; n < 4; ++n) {
            int c = wc * 64 + n * 16 + l15;
            float bv = (c < 64) ? bkv[p * 64 + c] : bkv[256 + p * 64 + (c - 64)];
#pragma unroll
            for (int j = 0; j < 4; ++j) {
                int r = wr * 64 + m * 16 + l4 * 4 + j;
                float v = acc[m][n][j] + bv;
                if (c < 64) {
                    v = (v > 0.f) ? v + 1.f : __expf(v);
                    KfT[c][r] = f2bf(v);
                } else {
                    VfT[c - 64][r] = f2bf(v);
                }
            }
        }
    __syncthreads();

    const int hl = wid & 1, dt = wid >> 1;
    f32x4 acc2[2] = {{0.f, 0.f, 0.f, 0.f}, {0.f, 0.f, 0.f, 0.f}};
#pragma unroll
    for (int kc = 0; kc < 4; ++kc) {
        s16x8 af = *(const s16x8*)&KfT[hl * 32 + dt * 16 + l15][kc * 32 + l4 * 8];
#pragma unroll
        for (int mt = 0; mt < 2; ++mt) {
            s16x8 bf = *(const s16x8*)&VfT[hl * 32 + mt * 16 + l15][kc * 32 + l4 * 8];
            acc2[mt] = __builtin_amdgcn_mfma_f32_16x16x32_bf16(af, bf, acc2[mt], 0, 0, 0);
        }
    }
    const int h = 2 * p + hl;
    float* pb = part + ((long)(b * 8 + h) * NCHUNK + chunk) * 1056;
#pragma unroll
    for (int mt = 0; mt < 2; ++mt)
#pragma unroll
        for (int j = 0; j < 4; ++j) {
            int d = dt * 16 + l4 * 4 + j;
            int mm = mt * 16 + l15;
            pb[d * 32 + mm] = acc2[mt][j];
        }
    if (tid < 64) {
        float s = 0.f;
#pragma unroll
        for (int rr = 0; rr < 16; ++rr) {
            s16x8 v8 = *(const s16x8*)&KfT[tid][rr * 8];
#pragma unroll
            for (int e = 0; e < 8; ++e) s += bf2f(v8[e]);
        }
        int hh = tid >> 5, dd = tid & 31;
        float* pb2 = part + ((long)(b * 8 + 2 * p + hh) * NCHUNK + chunk) * 1056;
        pb2[1024 + dd] = s;
    }
}

__global__ __launch_bounds__(256) void kvred_kernel(
    const float* __restrict__ part, float* __restrict__ kv, float* __restrict__ ksum)
{
    int bh = blockIdx.x, tid = threadIdx.x;
    const float* pb = part + (long)bh * NCHUNK * 1056;
    float s0 = 0, s1 = 0, s2 = 0, s3 = 0;
    for (int cc = 0; cc < NCHUNK; ++cc) {
        const float* ptr = pb + cc * 1056 + tid * 4;
        s0 += ptr[0]; s1 += ptr[1]; s2 += ptr[2]; s3 += ptr[3];
    }
    float* kb = kv + (long)bh * 1024 + tid * 4;
    kb[0] = s0; kb[1] = s1; kb[2] = s2; kb[3] = s3;
    if (tid < 32) {
        float ss = 0;
        for (int cc = 0; cc < NCHUNK; ++cc) ss += pb[cc * 1056 + 1024 + tid];
        ksum[bh * 32 + tid] = ss;
    }
}

// ---- fused FFN v4 (R15-proven): wave-private B staging, BM=64 ----
__global__ __launch_bounds__(512, 1) void ffnln_kernel(
    const short* __restrict__ X, const short* __restrict__ W1t,
    const float* __restrict__ b1, const short* __restrict__ W2t,
    const float* __restrict__ b2,
    const float* __restrict__ gam, const float* __restrict__ bet,
    const float* __restrict__ Fin, float* __restrict__ Fout,
    short* __restrict__ xb)
{
    __shared__ short xs[4][64][64];
    __shared__ short hs[4][64][64];
    __shared__ short Bs[8][2][32][64];
    __shared__ float partS[8][64];
    __shared__ float partQ[8][64];
    __shared__ float muA[64];
    __shared__ float rsA[64];
    const int tid = threadIdx.x;
    const int lane = tid & 63;
    const int w = tid >> 6;
    const int bm = xcd_chunk(blockIdx.x, gridDim.x) * 64;
    const int l15 = lane & 15, l4 = lane >> 4;
    const int rl = lane >> 3;
    const int ch = lane & 7;
    const int sw = l15 & 7;

#pragma unroll
    for (int j = 0; j < 4; ++j) {
        int s = w * 4 + j;
        int kt = s >> 3, rg = s & 7;
        int r = rg * 8 + rl;
        int cs = ch ^ (r & 7);
        GLDS16(X + (long)(bm + r) * 256 + kt * 64 + cs * 8, &xs[kt][rg * 8][0]);
    }
    auto STAGEB = [&](int buf, int v) {
        int hc = v >> 3, u = v & 7;
#pragma unroll
        for (int j = 0; j < 4; ++j) {
            int lr = j * 8 + rl;
            int r = w * 32 + lr;
            int cs = ch ^ (lr & 7);
            const short* src = (u < 4)
                ? W1t + (long)(hc * 256 + r) * 256 + u * 64 + cs * 8
                : W2t + (long)r * 1024 + hc * 256 + (u - 4) * 64 + cs * 8;
            GLDS16(src, &Bs[w][buf][j * 8][0]);
        }
    };

    STAGEB(0, 0);
    STAGEB(1, 1);
    asm volatile("s_waitcnt vmcnt(8)" ::: "memory");
    asm volatile("s_barrier" ::: "memory");

    f32x4 facc[4][2] = {};

    for (int hc = 0; hc < 4; ++hc) {
        f32x4 hacc[4][2] = {};
#pragma unroll
        for (int u = 0; u < 4; ++u) {
            const int v = hc * 8 + u;
            const int buf = v & 1;
            asm volatile("s_waitcnt vmcnt(4)" ::: "memory");
            s16x8 avA[2][4], avB[2][2];
#pragma unroll
            for (int kk = 0; kk < 2; ++kk) {
#pragma unroll
                for (int n = 0; n < 2; ++n)
                    avB[kk][n] = *(const s16x8*)&Bs[w][buf][n * 16 + l15][(((kk << 2) | l4) ^ sw) << 3];
#pragma unroll
                for (int m = 0; m < 4; ++m)
                    avA[kk][m] = *(const s16x8*)&xs[u][m * 16 + l15][(((kk << 2) | l4) ^ sw) << 3];
            }
            asm volatile("s_waitcnt lgkmcnt(0)" ::: "memory");
            STAGEB(buf, v + 2);
#pragma unroll
            for (int kk = 0; kk < 2; ++kk)
#pragma unroll
                for (int m = 0; m < 4; ++m)
#pragma unroll
                    for (int n = 0; n < 2; ++n)
                        hacc[m][n] = __builtin_amdgcn_mfma_f32_16x16x32_bf16(avA[kk][m], avB[kk][n], hacc[m][n], 0, 0, 0);
        }
        asm volatile("s_waitcnt lgkmcnt(0)" ::: "memory");
        asm volatile("s_barrier" ::: "memory");
#pragma unroll
        for (int m = 0; m < 4; ++m)
#pragma unroll
            for (int n = 0; n < 2; ++n) {
                int c = w * 32 + n * 16 + l15;
                float bv = b1[hc * 256 + c];
#pragma unroll
                for (int j = 0; j < 4; ++j) {
                    int r = m * 16 + l4 * 4 + j;
                    float hv = fmaxf(hacc[m][n][j] + bv, 0.f);
                    int kt = c >> 6, cc = (c & 63) >> 3;
                    hs[kt][r][((cc ^ (r & 7)) << 3) + (c & 7)] = f2bf(hv);
                }
            }
        asm volatile("s_waitcnt lgkmcnt(0)" ::: "memory");
        asm volatile("s_barrier" ::: "memory");
#pragma unroll
        for (int u = 4; u < 8; ++u) {
            const int v = hc * 8 + u;
            const int buf = v & 1;
            if (v < 31) { asm volatile("s_waitcnt vmcnt(4)" ::: "memory"); }
            else        { asm volatile("s_waitcnt vmcnt(0)" ::: "memory"); }
            s16x8 avA[2][4], avB[2][2];
#pragma unroll
            for (int kk = 0; kk < 2; ++kk) {
#pragma unroll
                for (int n = 0; n < 2; ++n)
                    avB[kk][n] = *(const s16x8*)&Bs[w][buf][n * 16 + l15][(((kk << 2) | l4) ^ sw) << 3];
#pragma unroll
                for (int m = 0; m < 4; ++m)
                    avA[kk][m] = *(const s16x8*)&hs[u - 4][m * 16 + l15][(((kk << 2) | l4) ^ sw) << 3];
            }
            asm volatile("s_waitcnt lgkmcnt(0)" ::: "memory");
            if (v + 2 < 32) STAGEB(buf, v + 2);
#pragma unroll
            for (int kk = 0; kk < 2; ++kk)
#pragma unroll
                for (int m = 0; m < 4; ++m)
#pragma unroll
                    for (int n = 0; n < 2; ++n)
                        facc[m][n] = __builtin_amdgcn_mfma_f32_16x16x32_bf16(avA[kk][m], avB[kk][n], facc[m][n], 0, 0, 0);
        }
    }

#pragma unroll
    for (int m = 0; m < 4; ++m)
#pragma unroll
        for (int n = 0; n < 2; ++n) {
            int col = w * 32 + n * 16 + l15;
            float bv = b2[col];
#pragma unroll
            for (int j = 0; j < 4; ++j) {
                int r = m * 16 + l4 * 4 + j;
                float v = fmaxf(facc[m][n][j] + bv, 0.f);
                v += Fin[(long)(bm + r) * DIM + col];
                facc[m][n][j] = v;
            }
        }
#pragma unroll
    for (int m = 0; m < 4; ++m)
#pragma unroll
        for (int j = 0; j < 4; ++j) {
            float s = facc[m][0][j] + facc[m][1][j];
            float q = facc[m][0][j] * facc[m][0][j] + facc[m][1][j] * facc[m][1][j];
#pragma unroll
            for (int off = 1; off < 16; off <<= 1) {
                s += __shfl_xor(s, off);
                q += __shfl_xor(q, off);
            }
            if (l15 == 0) {
                partS[w][m * 16 + l4 * 4 + j] = s;
                partQ[w][m * 16 + l4 * 4 + j] = q;
            }
        }
    __syncthreads();
    if (tid < 64) {
        float S = 0, Qq = 0;
#pragma unroll
        for (int ww = 0; ww < 8; ++ww) { S += partS[ww][tid]; Qq += partQ[ww][tid]; }
        float mu = S * (1.f / 256.f);
        float var = Qq * (1.f / 256.f) - mu * mu;
        muA[tid] = mu;
        rsA[tid] = rsqrtf(var + 1e-3f);
    }
    __syncthreads();
#pragma unroll
    for (int m = 0; m < 4; ++m)
#pragma unroll
        for (int j = 0; j < 4; ++j) {
            int r = m * 16 + l4 * 4 + j;
            float mu = muA[r], rs = rsA[r];
#pragma unroll
            for (int n = 0; n < 2; ++n) {
                int col = w * 32 + n * 16 + l15;
                float t = (facc[m][n][j] - mu) * rs * gam[col] + bet[col];
                long o = (long)(bm + r) * DIM + col;
                xb[o] = f2bf(t);
                Fout[o] = t;
            }
        }
}

// ---- MEGA-fused qattn (R16-proven, R19-measured form) ----
__global__ __launch_bounds__(512, 1) void qattn_kernel(
    const short* __restrict__ A, const short* __restrict__ Bt,
    const float* __restrict__ bias, const float* __restrict__ kv,
    const float* __restrict__ ksum,
    const short* __restrict__ WoT, const float* __restrict__ bo,
    const float* __restrict__ gam, const float* __restrict__ bet,
    const float* __restrict__ Fin, float* __restrict__ Fout,
    short* __restrict__ xb)
{
    __shared__ char smem[140288];
    short (*As)[128][64] = (short(*)[128][64])(smem);
    short (*Bs)[256][64] = (short(*)[256][64])(smem + 32768);
    short (*QfL)[256] = (short(*)[256])(smem);
    short (*kvbT)[32][48] = (short(*)[32][48])(smem + 98304);
    float* ksumAll = (float*)(smem + 122880);
    float (*partDenH)[128] = (float(*)[128])(smem + 123904);
    short (*oL)[256] = (short(*)[256])(smem + 65536);
    short (*WoS)[256][64] = (short(*)[256][64])(smem);
    float (*partS)[128] = (float(*)[128])(smem + 131072);
    float (*partQ)[128] = (float(*)[128])(smem + 135168);
    float* muA = (float*)(smem + 139264);
    float* rsA = (float*)(smem + 139776);

    const int tid = threadIdx.x;
    const int lane = tid & 63;
    const int w = tid >> 6;
    const int wr = w >> 2, wc = w & 3;
    const int bm = xcd_chunk(blockIdx.x, gridDim.x) * 128;
    const int b = bm >> 12;
    const int l15 = lane & 15, l4 = lane >> 4;
    const int rl = lane >> 3;
    const int ch = lane & 7;
    const int sw = l15 & 7;

    for (int idx = tid; idx < 8192; idx += 512) {
        int h = idx >> 10, j = idx & 1023, d = j >> 5, m = j & 31;
        kvbT[h][m][d] = f2bf(kv[(long)(b * 8 + h) * 1024 + j]);
    }
    if (tid < 256) ksumAll[tid] = ksum[(b * 8 + (tid >> 5)) * 32 + (tid & 31)];

    auto STAGE = [&](int buf, int t) {
        const int k0 = t << 6;
#pragma unroll
        for (int j = 0; j < 6; ++j) {
            int s = w * 6 + j;
            if (s < 16) {
                int r = s * 8 + rl;
                int cs = ch ^ (r & 7);
                GLDS16(A + (long)(bm + r) * 256 + k0 + cs * 8, &As[buf][s * 8][0]);
            } else {
                int r = (s - 16) * 8 + rl;
                int cs = ch ^ (r & 7);
                GLDS16(Bt + (long)r * 256 + k0 + cs * 8, &Bs[buf][(s - 16) * 8][0]);
            }
        }
    };

    f32x4 acc[4][4] = {};

    STAGE(0, 0);
    STAGE(1, 1);
#pragma unroll
    for (int t = 0; t < 4; ++t) {
        const int buf = t & 1;
        if (t < 3) { asm volatile("s_waitcnt vmcnt(6)" ::: "memory"); }
        else       { asm volatile("s_waitcnt vmcnt(0)" ::: "memory"); }
        asm volatile("s_barrier" ::: "memory");
        s16x8 avA[2][4], avB[2][4];
#pragma unroll
        for (int kk = 0; kk < 2; ++kk) {
#pragma unroll
            for (int m = 0; m < 4; ++m)
                avA[kk][m] = *(const s16x8*)&As[buf][wr * 64 + m * 16 + l15][(((kk << 2) | l4) ^ sw) << 3];
#pragma unroll
            for (int n = 0; n < 4; ++n)
                avB[kk][n] = *(const s16x8*)&Bs[buf][wc * 64 + n * 16 + l15][(((kk << 2) | l4) ^ sw) << 3];
        }
        asm volatile("s_waitcnt lgkmcnt(0)" ::: "memory");
        asm volatile("s_barrier" ::: "memory");
        if (t < 2) STAGE(buf, t + 2);
#pragma unroll
        for (int kk = 0; kk < 2; ++kk)
#pragma unroll
            for (int m = 0; m < 4; ++m)
#pragma unroll
                for (int n = 0; n < 4; ++n)
                    acc[m][n] = __builtin_amdgcn_mfma_f32_16x16x32_bf16(avA[kk][m], avB[kk][n], acc[m][n], 0, 0, 0);
    }

    // phase 1.5
#pragma unroll
    for (int m = 0; m < 4; ++m)
#pragma unroll
        for (int n = 0; n < 4; ++n) {
            int col = wc * 64 + n * 16 + l15;
            float bv = bias[col];
#pragma unroll
            for (int j = 0; j < 4; ++j) {
                float v = acc[m][n][j] + bv;
                acc[m][n][j] = (v > 0.f) ? v + 1.f : __expf(v);
            }
        }
#pragma unroll
    for (int m = 0; m < 4; ++m)
#pragma unroll
        for (int j = 0; j < 4; ++j) {
            float p0 = acc[m][0][j] * ksumAll[wc * 64 + l15]
                     + acc[m][1][j] * ksumAll[wc * 64 + 16 + l15];
            float p1 = acc[m][2][j] * ksumAll[wc * 64 + 32 + l15]
                     + acc[m][3][j] * ksumAll[wc * 64 + 48 + l15];
#pragma unroll
            for (int off = 1; off < 16; off <<= 1) {
                p0 += __shfl_xor(p0, off);
                p1 += __shfl_xor(p1, off);
            }
            if (l15 == 0) {
                int r = wr * 64 + m * 16 + l4 * 4 + j;
                partDenH[wc * 2 + 0][r] = p0;
                partDenH[wc * 2 + 1][r] = p1;
            }
        }
#pragma unroll
    for (int m = 0; m < 4; ++m)
#pragma unroll
        for (int n = 0; n < 4; ++n) {
            int col = wc * 64 + n * 16 + l15;
#pragma unroll
            for (int j = 0; j < 4; ++j) {
                int r = wr * 64 + m * 16 + l4 * 4 + j;
                int chunk = (col >> 3) ^ (r & 7);
                QfL[r][chunk * 8 + (col & 7)] = f2bf(acc[m][n][j]);
            }
        }
    __syncthreads();

    // phase 2 preload (kvbT + partDenH die after this; oL overlays them)
    const int h = w;
    s16x8 afr[2];
#pragma unroll
    for (int ct = 0; ct < 2; ++ct)
        afr[ct] = *(const s16x8*)&kvbT[h][ct * 16 + l15][l4 * 8];
    float zv[8];
#pragma unroll
    for (int rt = 0; rt < 8; ++rt)
        zv[rt] = 1.f / (partDenH[h][rt * 16 + l15] + 1e-6f);
    asm volatile("s_waitcnt lgkmcnt(0)" ::: "memory");
    __syncthreads();

    // phase 2
#pragma unroll
    for (int rt = 0; rt < 8; ++rt) {
        int r = rt * 16 + l15;
        int qchunk = (h * 4 + l4) ^ (r & 7);
        s16x8 bfr = *(const s16x8*)&QfL[r][qchunk * 8];
#pragma unroll
        for (int ct = 0; ct < 2; ++ct) {
            f32x4 zero = {0.f, 0.f, 0.f, 0.f};
            f32x4 po = __builtin_amdgcn_mfma_f32_16x16x32_bf16(afr[ct], bfr, zero, 0, 0, 0);
            s16x4 o4;
#pragma unroll
            for (int j = 0; j < 4; ++j) o4[j] = f2bf(po[j] * zv[rt]);
            int c0 = h * 32 + ct * 16 + l4 * 4;
            int cc = c0 >> 3;
            *(s16x4*)&oL[r][((cc ^ (r & 7)) << 3) + (c0 & 7)] = o4;
        }
    }
    asm volatile("s_waitcnt lgkmcnt(0)" ::: "memory");
    __syncthreads();

    // phase 3
    auto STAGEWO = [&](int buf, int t) {
#pragma unroll
        for (int j = 0; j < 4; ++j) {
            int lr = j * 8 + rl;
            int r = w * 32 + lr;
            int cs = ch ^ (lr & 7);
            GLDS16(WoT + (long)r * 256 + t * 64 + cs * 8, &WoS[buf][w * 32 + j * 8][0]);
        }
    };
    STAGEWO(0, 0);
    STAGEWO(1, 1);

    f32x4 facc[8][2] = {};
#pragma unroll
    for (int t = 0; t < 4; ++t) {
        const int buf = t & 1;
        if (t < 3) { asm volatile("s_waitcnt vmcnt(4)" ::: "memory"); }
        else       { asm volatile("s_waitcnt vmcnt(0)" ::: "memory"); }
#pragma unroll
        for (int kk = 0; kk < 2; ++kk) {
            s16x8 avB0 = *(const s16x8*)&WoS[buf][w * 32 + l15][(((kk << 2) | l4) ^ sw) << 3];
            s16x8 avB1 = *(const s16x8*)&WoS[buf][w * 32 + 16 + l15][(((kk << 2) | l4) ^ sw) << 3];
#pragma unroll
            for (int m = 0; m < 8; ++m) {
                int ar = m * 16 + l15;
                s16x8 avA = *(const s16x8*)&oL[ar][(t * 8 + (((kk << 2) | l4) ^ sw)) << 3];
                facc[m][0] = __builtin_amdgcn_mfma_f32_16x16x32_bf16(avA, avB0, facc[m][0], 0, 0, 0);
                facc[m][1] = __builtin_amdgcn_mfma_f32_16x16x32_bf16(avA, avB1, facc[m][1], 0, 0, 0);
            }
        }
        asm volatile("s_waitcnt lgkmcnt(0)" ::: "memory");
        if (t + 2 < 4) STAGEWO(buf, t + 2);
    }

    // epilogue: bias + fp32 residual, row LN over 128 rows
#pragma unroll
    for (int m = 0; m < 8; ++m)
#pragma unroll
        for (int n = 0; n < 2; ++n) {
            int col = w * 32 + n * 16 + l15;
            float bv = bo[col];
#pragma unroll
            for (int j = 0; j < 4; ++j) {
                int r = m * 16 + l4 * 4 + j;
                float v = facc[m][n][j] + bv;
                v += Fin[(long)(bm + r) * DIM + col];
                facc[m][n][j] = v;
            }
        }
#pragma unroll
    for (int m = 0; m < 8; ++m)
#pragma unroll
        for (int j = 0; j < 4; ++j) {
            float s = facc[m][0][j] + facc[m][1][j];
            float q = facc[m][0][j] * facc[m][0][j] + facc[m][1][j] * facc[m][1][j];
#pragma unroll
            for (int off = 1; off < 16; off <<= 1) {
                s += __shfl_xor(s, off);
                q += __shfl_xor(q, off);
            }
            if (l15 == 0) {
                partS[w][m * 16 + l4 * 4 + j] = s;
                partQ[w][m * 16 + l4 * 4 + j] = q;
            }
        }
    __syncthreads();
    if (tid < 128) {
        float S = 0, Qq = 0;
#pragma unroll
        for (int ww = 0; ww < 8; ++ww) { S += partS[ww][tid]; Qq += partQ[ww][tid]; }
        float mu = S * (1.f / 256.f);
        float var = Qq * (1.f / 256.f) - mu * mu;
        muA[tid] = mu;
        rsA[tid] = rsqrtf(var + 1e-3f);
    }
    __syncthreads();
#pragma unroll
    for (int m = 0; m < 8; ++m)
#pragma unroll
        for (int j = 0; j < 4; ++j) {
            int r = m * 16 + l4 * 4 + j;
            float mu = muA[r], rs = rsA[r];
#pragma unroll
            for (int n = 0; n < 2; ++n) {
                int col = w * 32 + n * 16 + l15;
                float t = (facc[m][n][j] - mu) * rs * gam[col] + bet[col];
                long o = (long)(bm + r) * DIM + col;
                xb[o] = f2bf(t);
                Fout[o] = t;
            }
        }
}

// =======================================================================================
extern "C" void kernel_launch(void* const* d_in, const int* in_sizes, int n_in,
                              void* d_out, int out_size, void* d_ws, size_t ws_size,
                              hipStream_t stream)
{
    const float* Qin = (const float*)d_in[0];
    const float* Kin = (const float*)d_in[1];
    const float* Wq1 = (const float*)d_in[2];
    const float* Wk1 = (const float*)d_in[3];
    const float* Wv1 = (const float*)d_in[4];
    const float* Wo1 = (const float*)d_in[5];
    const float* bq1 = (const float*)d_in[6];
    const float* bk1 = (const float*)d_in[7];
    const float* bv1 = (const float*)d_in[8];
    const float* bo1 = (const float*)d_in[9];
    const float* Wq2 = (const float*)d_in[10];
    const float* Wk2 = (const float*)d_in[11];
    const float* Wv2 = (const float*)d_in[12];
    const float* Wo2 = (const float*)d_in[13];
    const float* bq2 = (const float*)d_in[14];
    const float* bk2 = (const float*)d_in[15];
    const float* bv2 = (const float*)d_in[16];
    const float* bo2 = (const float*)d_in[17];
    const float* Wf1 = (const float*)d_in[18];
    const float* bf1 = (const float*)d_in[19];
    const float* Wf2 = (const float*)d_in[20];
    const float* bf2 = (const float*)d_in[21];
    const float* ln1g = (const float*)d_in[22];
    const float* ln1b = (const float*)d_in[23];
    const float* ln2g = (const float*)d_in[24];
    const float* ln2b = (const float*)d_in[25];
    const float* ln3g = (const float*)d_in[26];
    const float* ln3b = (const float*)d_in[27];
    (void)in_sizes; (void)n_in; (void)out_size;

    const size_t NEED = 117841920ULL;   // round-2-proven guard (actual use ~95 MB)
    if (ws_size < NEED) return;

    char* ws = (char*)d_ws;
    size_t off = 0;
    auto alloc = [&](size_t bytes) -> void* {
        void* p = ws + off;
        off = (off + bytes + 255) & ~(size_t)255;
        return p;
    };
    const size_t ACT_E = (size_t)M_TOTAL * DIM;

    short* wkv1t = (short*)alloc((size_t)NL * 512 * 256 * 2);
    short* wkv2t = (short*)alloc((size_t)NL * 512 * 256 * 2);
    short* wq1t  = (short*)alloc((size_t)NL * 65536 * 2);
    short* wo1t  = (short*)alloc((size_t)NL * 65536 * 2);
    short* wq2t  = (short*)alloc((size_t)NL * 65536 * 2);
    short* wo2t  = (short*)alloc((size_t)NL * 65536 * 2);
    short* wf1t  = (short*)alloc((size_t)NL * 262144 * 2);
    short* wf2t  = (short*)alloc((size_t)NL * 262144 * 2);
    float* bkv1  = (float*)alloc((size_t)NL * 512 * 4);
    float* bkv2  = (float*)alloc((size_t)NL * 512 * 4);
    short* kbf = (short*)alloc(ACT_E * 2);
    short* A0  = (short*)alloc(ACT_E * 2);          // bf16 trunk mirror (GEMM inputs)
    float* Fx  = (float*)alloc(ACT_E * 4);          // fp32 residual trunk
    float* part = (float*)alloc((size_t)64 * NCHUNK * 1056 * 4);
    float* kvb  = (float*)alloc((size_t)64 * 1024 * 4);
    float* ksb  = (float*)alloc((size_t)64 * 32 * 4);

    peadd_kernel<<<2048, 256, 0, stream>>>(Qin, A0, Fx, (int)ACT_E);
    kconv_kernel<<<2048, 256, 0, stream>>>(Kin, kbf, (int)ACT_E);
    wtrans_kernel<<<dim3(8, 8, NL), dim3(32, 8), 0, stream>>>(Wk1, wkv1t, 256, 256, 512 * 256, 0);
    wtrans_kernel<<<dim3(8, 8, NL), dim3(32, 8), 0, stream>>>(Wv1, wkv1t, 256, 256, 512 * 256, 256);
    wtrans_kernel<<<dim3(8, 8, NL), dim3(32, 8), 0, stream>>>(Wk2, wkv2t, 256, 256, 512 * 256, 0);
    wtrans_kernel<<<dim3(8, 8, NL), dim3(32, 8), 0, stream>>>(Wv2, wkv2t, 256, 256, 512 * 256, 256);
    wtrans_kernel<<<dim3(8, 8, NL), dim3(32, 8), 0, stream>>>(Wq1, wq1t, 256, 256, 65536, 0);
    wtrans_kernel<<<dim3(8, 8, NL), dim3(32, 8), 0, stream>>>(Wo1, wo1t, 256, 256, 65536, 0);
    wtrans_kernel<<<dim3(8, 8, NL), dim3(32, 8), 0, stream>>>(Wq2, wq2t, 256, 256, 65536, 0);
    wtrans_kernel<<<dim3(8, 8, NL), dim3(32, 8), 0, stream>>>(Wo2, wo2t, 256, 256, 65536, 0);
    wtrans_kernel<<<dim3(8, 32, NL), dim3(32, 8), 0, stream>>>(Wf1, wf1t, 256, 1024, 262144, 0);
    wtrans_kernel<<<dim3(32, 8, NL), dim3(32, 8), 0, stream>>>(Wf2, wf2t, 1024, 256, 262144, 0);
    bpack_kernel<<<NL, 512, 0, stream>>>(bk1, bv1, bk2, bv2, bkv1, bkv2);

    dim3 blk(256), blk512(512);

    for (int i = 0; i < NL; ++i) {
        const short* wkv1i = wkv1t + (size_t)i * 512 * 256;
        const short* wkv2i = wkv2t + (size_t)i * 512 * 256;
        const short* wq1i = wq1t + (size_t)i * 65536;
        const short* wo1i = wo1t + (size_t)i * 65536;
        const short* wq2i = wq2t + (size_t)i * 65536;
        const short* wo2i = wo2t + (size_t)i * 65536;
        const short* wf1i = wf1t + (size_t)i * 262144;
        const short* wf2i = wf2t + (size_t)i * 262144;

        // ---- self linear-attention (x1 -> x2): 3 dispatches
        kvproj_kernel<<<dim3(256, 4), blk, 0, stream>>>(A0, wkv1i, bkv1 + i * 512, part);
        kvred_kernel<<<64, blk, 0, stream>>>(part, kvb, ksb);
        qattn_kernel<<<M_TOTAL / 128, blk512, 0, stream>>>(A0, wq1i, bq1 + i * 256, kvb, ksb,
            wo1i, bo1 + i * 256, ln1g + i * 256, ln1b + i * 256, Fx, Fx, A0);

        // ---- cross linear-attention (x2, K -> x3): 3 dispatches
        kvproj_kernel<<<dim3(256, 4), blk, 0, stream>>>(kbf, wkv2i, bkv2 + i * 512, part);
        kvred_kernel<<<64, blk, 0, stream>>>(part, kvb, ksb);
        qattn_kernel<<<M_TOTAL / 128, blk512, 0, stream>>>(A0, wq2i, bq2 + i * 256, kvb, ksb,
            wo2i, bo2 + i * 256, ln2g + i * 256, ln2b + i * 256, Fx, Fx, A0);

        // ---- fused FFN + LN (x3 -> x1'): 1 dispatch
        ffnln_kernel<<<M_TOTAL / 64, blk512, 0, stream>>>(A0, wf1i, bf1 + i * 1024,
            wf2i, bf2 + i * 256, ln3g + i * 256, ln3b + i * 256,
            Fx, (i == NL - 1) ? (float*)d_out : Fx, A0);
    }
}